// Round 4
// baseline (1138.210 us; speedup 1.0000x reference)
//
#include <hip/hip_runtime.h>

#define SLOPE 0.2f
#define NEG_INF -3.4e38f

__device__ __forceinline__ float lrelu(float v) { return v >= 0.f ? v : SLOPE * v; }

// ============================================================================
// xp = x @ W (K -> 128 = 2 heads * 64) fused with attention dots.
// Persistent: wave-pair per node (wave h = head h); W column in registers.
// ============================================================================
template <int K>
__global__ void k_xp(const float* __restrict__ x, const float* __restrict__ W,
                     const float* __restrict__ as_, const float* __restrict__ ad_,
                     float* __restrict__ xp, float* __restrict__ asrc,
                     float* __restrict__ adst, int N) {
    int tid = blockIdx.x * blockDim.x + threadIdx.x;
    int lane = threadIdx.x & 63;
    int h = (threadIdx.x >> 6) & 1;
    int pair = tid >> 7;
    int npairs = (gridDim.x * blockDim.x) >> 7;
    int c = h * 64 + lane;

    float wreg[K];
    #pragma unroll
    for (int k = 0; k < K; ++k) wreg[k] = W[k * 128 + c];
    float asv = as_[c], adv = ad_[c];

    for (int n = pair; n < N; n += npairs) {
        float xv = (lane < K) ? x[(size_t)n * K + lane] : 0.f;
        float acc0 = 0.f, acc1 = 0.f;
        #pragma unroll
        for (int k = 0; k < K; k += 2) {
            acc0 += __shfl(xv, k, 64) * wreg[k];
            if (k + 1 < K) acc1 += __shfl(xv, k + 1, 64) * wreg[k + 1];
        }
        float acc = acc0 + acc1;
        xp[(size_t)n * 128 + c] = acc;
        float ps = acc * asv, pd = acc * adv;
        for (int off = 32; off > 0; off >>= 1) {
            ps += __shfl_xor(ps, off, 64);
            pd += __shfl_xor(pd, off, 64);
        }
        if (lane == 0) { asrc[n * 2 + h] = ps; adst[n * 2 + h] = pd; }
    }
}

// ============================================================================
// CSR build: histogram -> exclusive scan -> scatter (counting sort by dst)
// ============================================================================
__global__ void k_hist(const int* __restrict__ dst, int* __restrict__ deg, int E) {
    for (int e = blockIdx.x * blockDim.x + threadIdx.x; e < E; e += gridDim.x * blockDim.x)
        atomicAdd(&deg[dst[e]], 1);
}

__global__ void k_scan_partial(const int* __restrict__ deg, int* __restrict__ partial, int N) {
    int b = blockIdx.x, t = threadIdx.x;
    int base = b * 1024 + t * 4;
    int s = 0;
    for (int i = 0; i < 4; ++i) { int idx = base + i; if (idx < N) s += deg[idx]; }
    __shared__ int sh[256];
    sh[t] = s; __syncthreads();
    for (int off = 128; off > 0; off >>= 1) { if (t < off) sh[t] += sh[t + off]; __syncthreads(); }
    if (t == 0) partial[b] = sh[0];
}

__global__ void k_scan_partials(int* __restrict__ partial, int nb) {
    __shared__ int sh[256];
    __shared__ int carry;
    int t = threadIdx.x;
    if (t == 0) carry = 0;
    __syncthreads();
    for (int base = 0; base < nb; base += 256) {
        int idx = base + t;
        int orig = (idx < nb) ? partial[idx] : 0;
        sh[t] = orig; __syncthreads();
        for (int off = 1; off < 256; off <<= 1) {
            int v = (t >= off) ? sh[t - off] : 0;
            __syncthreads();
            sh[t] += v;
            __syncthreads();
        }
        if (idx < nb) partial[idx] = carry + sh[t] - orig;
        __syncthreads();
        if (t == 0) carry += sh[255];
        __syncthreads();
    }
}

__global__ void k_scan_final(const int* __restrict__ deg, const int* __restrict__ partial,
                             int* __restrict__ rowptr, int N, int E) {
    int b = blockIdx.x, t = threadIdx.x;
    int base = b * 1024 + t * 4;
    int local[4]; int s = 0;
    for (int i = 0; i < 4; ++i) { int idx = base + i; local[i] = (idx < N) ? deg[idx] : 0; s += local[i]; }
    __shared__ int sh[256];
    int orig = s;
    sh[t] = s; __syncthreads();
    for (int off = 1; off < 256; off <<= 1) {
        int v = (t >= off) ? sh[t - off] : 0;
        __syncthreads();
        sh[t] += v;
        __syncthreads();
    }
    int run = partial[b] + sh[t] - orig;
    for (int i = 0; i < 4; ++i) {
        int idx = base + i;
        if (idx < N) rowptr[idx] = run;
        run += local[i];
    }
    if (b == 0 && t == 0) rowptr[N] = E;
}

__global__ void k_scatter(const int* __restrict__ src, const int* __restrict__ dst,
                          const int* __restrict__ rowptr, int* __restrict__ cur,
                          int* __restrict__ csr_src, int E) {
    for (int e = blockIdx.x * blockDim.x + threadIdx.x; e < E; e += gridDim.x * blockDim.x) {
        int d = dst[e];
        int pos = atomicAdd(&cur[d], 1);
        csr_src[rowptr[d] + pos] = src[e];
    }
}

// ============================================================================
// Per-node softmax -> alpha planes. Persistent wave-pair per node (wave=head).
// alpha: [2][E] head-major; aself: [2][N].
// ============================================================================
__global__ void k_node_alpha(const int* __restrict__ rowptr, const int* __restrict__ csr_src,
                             const float* __restrict__ asrc, const float* __restrict__ adst,
                             float* __restrict__ alpha, float* __restrict__ aself,
                             int N, int E) {
    int tid = blockIdx.x * blockDim.x + threadIdx.x;
    int lane = threadIdx.x & 63;
    int h = (threadIdx.x >> 6) & 1;
    int pair = tid >> 7;
    int npairs = (gridDim.x * blockDim.x) >> 7;

    for (int n = pair; n < N; n += npairs) {
        int rs = rowptr[n], re = rowptr[n + 1], cnt = re - rs;
        float a_dst = adst[n * 2 + h];
        float v_self = lrelu(asrc[n * 2 + h] + a_dst);

        if (cnt <= 64) {
            float v = NEG_INF;
            if (lane < cnt) {
                int s = csr_src[rs + lane];
                v = lrelu(asrc[s * 2 + h] + a_dst);
            }
            float m = fmaxf(v, v_self);
            for (int off = 32; off > 0; off >>= 1) m = fmaxf(m, __shfl_xor(m, off, 64));
            float ex = (lane < cnt) ? __expf(v - m) : 0.f;
            float exs = __expf(v_self - m);
            float den = ex + (lane == 0 ? exs : 0.f);
            for (int off = 32; off > 0; off >>= 1) den += __shfl_xor(den, off, 64);
            float inv = 1.f / (den + 1e-16f);
            if (lane < cnt) alpha[(size_t)h * E + rs + lane] = ex * inv;
            if (lane == 0) aself[(size_t)h * N + n] = exs * inv;
        } else {
            float m = v_self;
            for (int e = rs + lane; e < re; e += 64) {
                int s = csr_src[e];
                m = fmaxf(m, lrelu(asrc[s * 2 + h] + a_dst));
            }
            for (int off = 32; off > 0; off >>= 1) m = fmaxf(m, __shfl_xor(m, off, 64));
            float den = (lane == 0) ? __expf(v_self - m) : 0.f;
            for (int e = rs + lane; e < re; e += 64) {
                int s = csr_src[e];
                den += __expf(lrelu(asrc[s * 2 + h] + a_dst) - m);
            }
            for (int off = 32; off > 0; off >>= 1) den += __shfl_xor(den, off, 64);
            float inv = 1.f / (den + 1e-16f);
            for (int e = rs + lane; e < re; e += 64) {
                int s = csr_src[e];
                alpha[(size_t)h * E + e] = __expf(lrelu(asrc[s * 2 + h] + a_dst) - m) * inv;
            }
            if (lane == 0) aself[(size_t)h * N + n] = __expf(v_self - m) * inv;
        }
    }
}

// ============================================================================
// Weighted gather: ONE wave per node, both heads. 4 lane-groups of 16:
// group g -> head (g&1), edge offset (g>>1); 2 edges x 2 heads per iter.
// xor-shuffle combine; head-mean + bias + relu; lanes 0..15 store float4.
// ============================================================================
__global__ void k_gather(const int* __restrict__ rowptr, const int* __restrict__ csr_src,
                         const float* __restrict__ alpha, const float* __restrict__ aself,
                         const float* __restrict__ xp, const float* __restrict__ b,
                         float* __restrict__ hout, int N, int E) {
    int tid = blockIdx.x * blockDim.x + threadIdx.x;
    int lane = threadIdx.x & 63;
    int wid = tid >> 6;
    int nw = (gridDim.x * blockDim.x) >> 6;
    int g = lane >> 4, c4 = lane & 15;
    int h = g & 1, eo = g >> 1;
    const float4* xp4 = (const float4*)xp;
    float4 bb = ((const float4*)b)[c4];

    for (int n = wid; n < N; n += nw) {
        int rs = rowptr[n], re = rowptr[n + 1];
        float4 acc = make_float4(0.f, 0.f, 0.f, 0.f);
        if (eo == 0) {                       // self contribution on groups 0,1
            float a0 = aself[(size_t)h * N + n];
            float4 v = xp4[(size_t)n * 32 + h * 16 + c4];
            acc.x = a0 * v.x; acc.y = a0 * v.y; acc.z = a0 * v.z; acc.w = a0 * v.w;
        }
        for (int e0 = rs; e0 < re; e0 += 2) {
            int e = e0 + eo;
            bool valid = e < re;
            int s = valid ? csr_src[e] : n;
            float a = valid ? alpha[(size_t)h * E + e] : 0.f;
            float4 v = xp4[(size_t)s * 32 + h * 16 + c4];
            acc.x += a * v.x; acc.y += a * v.y; acc.z += a * v.z; acc.w += a * v.w;
        }
        // combine even/odd edge groups (lane ^ 32), then heads (lane ^ 16)
        acc.x += __shfl_xor(acc.x, 32, 64);
        acc.y += __shfl_xor(acc.y, 32, 64);
        acc.z += __shfl_xor(acc.z, 32, 64);
        acc.w += __shfl_xor(acc.w, 32, 64);
        acc.x += __shfl_xor(acc.x, 16, 64);
        acc.y += __shfl_xor(acc.y, 16, 64);
        acc.z += __shfl_xor(acc.z, 16, 64);
        acc.w += __shfl_xor(acc.w, 16, 64);
        if (g == 0) {
            float4 r;
            r.x = fmaxf(acc.x * 0.5f + bb.x, 0.f);
            r.y = fmaxf(acc.y * 0.5f + bb.y, 0.f);
            r.z = fmaxf(acc.z * 0.5f + bb.z, 0.f);
            r.w = fmaxf(acc.w * 0.5f + bb.w, 0.f);
            ((float4*)hout)[(size_t)n * 16 + c4] = r;
        }
    }
}

// climber embed: relu(climber @ Wc + bc), [G,64]
__global__ void k_climber(const float* __restrict__ climber, const float* __restrict__ Wc,
                          const float* __restrict__ bc, float* __restrict__ cemb, int g64) {
    int i = blockIdx.x * blockDim.x + threadIdx.x;
    if (i >= g64) return;
    int g = i >> 6, c = i & 63;
    float acc = bc[c];
    for (int k = 0; k < 4; ++k) acc += climber[g * 4 + k] * Wc[k * 64 + c];
    cemb[i] = acc > 0.f ? acc : 0.f;
}

// ============================================================================
// Final MLP: persistent, one wave per node. Wm1 column (128) in registers,
// z broadcast via shuffles; 64->4 stage via float4 butterfly reduce.
// ============================================================================
__global__ void k_final(const float* __restrict__ h2, const float* __restrict__ cemb,
                        const int* __restrict__ batch, const float* __restrict__ Wm1,
                        const float* __restrict__ bm1, const float* __restrict__ Wm2,
                        const float* __restrict__ bm2, float* __restrict__ out, int N) {
    int tid = blockIdx.x * blockDim.x + threadIdx.x;
    int lane = threadIdx.x & 63;
    int wid = tid >> 6;
    int nw = (gridDim.x * blockDim.x) >> 6;

    float w1[128];
    #pragma unroll
    for (int k = 0; k < 128; ++k) w1[k] = Wm1[k * 64 + lane];
    float bm1v = bm1[lane];
    float4 w2 = ((const float4*)Wm2)[lane];
    float4 bm2v = *((const float4*)bm2);

    for (int n = wid; n < N; n += nw) {
        float z0 = h2[(size_t)n * 64 + lane];
        float z1 = cemb[(size_t)batch[n] * 64 + lane];
        float acc0 = 0.f, acc1 = 0.f;
        #pragma unroll
        for (int k = 0; k < 64; k += 2) {
            acc0 += __shfl(z0, k, 64) * w1[k];
            acc1 += __shfl(z0, k + 1, 64) * w1[k + 1];
        }
        #pragma unroll
        for (int k = 0; k < 64; k += 2) {
            acc0 += __shfl(z1, k, 64) * w1[64 + k];
            acc1 += __shfl(z1, k + 1, 64) * w1[64 + k + 1];
        }
        float m = acc0 + acc1 + bm1v;
        m = m > 0.f ? m : 0.f;
        float4 p;
        p.x = m * w2.x; p.y = m * w2.y; p.z = m * w2.z; p.w = m * w2.w;
        for (int off = 32; off > 0; off >>= 1) {
            p.x += __shfl_xor(p.x, off, 64);
            p.y += __shfl_xor(p.y, off, 64);
            p.z += __shfl_xor(p.z, off, 64);
            p.w += __shfl_xor(p.w, off, 64);
        }
        if (lane == 0) {
            float4 o;
            o.x = p.x + bm2v.x; o.y = p.y + bm2v.y;
            o.z = p.z + bm2v.z; o.w = p.w + bm2v.w;
            ((float4*)out)[n] = o;
        }
    }
}

extern "C" void kernel_launch(void* const* d_in, const int* in_sizes, int n_in,
                              void* d_out, int out_size, void* d_ws, size_t ws_size,
                              hipStream_t stream) {
    const float* x       = (const float*)d_in[0];
    const int*   ei      = (const int*)  d_in[1];
    const int*   batch   = (const int*)  d_in[2];
    const float* climber = (const float*)d_in[3];
    const float* W1  = (const float*)d_in[4];
    const float* as1 = (const float*)d_in[5];
    const float* ad1 = (const float*)d_in[6];
    const float* b1  = (const float*)d_in[7];
    const float* W2  = (const float*)d_in[8];
    const float* as2 = (const float*)d_in[9];
    const float* ad2 = (const float*)d_in[10];
    const float* b2  = (const float*)d_in[11];
    const float* Wc  = (const float*)d_in[12];
    const float* bc  = (const float*)d_in[13];
    const float* Wm1 = (const float*)d_in[14];
    const float* bm1 = (const float*)d_in[15];
    const float* Wm2 = (const float*)d_in[16];
    const float* bm2 = (const float*)d_in[17];

    const int N  = in_sizes[0] / 6;
    const int E  = in_sizes[1] / 2;
    const int G  = in_sizes[3] / 4;

    const int* srcI = ei;
    const int* dstI = ei + E;

    // ---------------- workspace carve ----------------
    char* base = (char*)d_ws;
    size_t off = 0;
    auto carve = [&](size_t bytes) { void* p = base + off; off += (bytes + 255) & ~size_t(255); return p; };
    float* xp      = (float*)carve((size_t)N * 128 * 4);
    float* hbuf    = (float*)carve((size_t)N * 64 * 4);
    float* asrc    = (float*)carve((size_t)N * 2 * 4);
    float* adst    = (float*)carve((size_t)N * 2 * 4);
    float* cemb    = (float*)carve((size_t)G * 64 * 4);
    int*   deg     = (int*)  carve((size_t)N * 4);
    int*   rowptr  = (int*)  carve((size_t)(N + 1) * 4);
    int*   cur     = (int*)  carve((size_t)N * 4);
    int*   partial = (int*)  carve(4096 * 4);
    int*   csr_src = (int*)  carve((size_t)E * 4);
    float* alpha   = (float*)carve((size_t)E * 2 * 4);
    float* aself   = (float*)carve((size_t)N * 2 * 4);

    const int tpb = 256;
    const int nScanBlk = (N + 1023) / 1024;
    const int PG = 2048;   // persistent grid blocks

    // ---------------- CSR build (shared by both layers) ----------------
    hipMemsetAsync(deg, 0, (size_t)N * 4, stream);
    hipMemsetAsync(cur, 0, (size_t)N * 4, stream);
    k_hist<<<1024, tpb, 0, stream>>>(dstI, deg, E);
    k_scan_partial<<<nScanBlk, tpb, 0, stream>>>(deg, partial, N);
    k_scan_partials<<<1, tpb, 0, stream>>>(partial, nScanBlk);
    k_scan_final<<<nScanBlk, tpb, 0, stream>>>(deg, partial, rowptr, N, E);
    k_scatter<<<1024, tpb, 0, stream>>>(srcI, dstI, rowptr, cur, csr_src, E);

    // ---------------- layer 1 ----------------
    k_xp<6><<<PG, tpb, 0, stream>>>(x, W1, as1, ad1, xp, asrc, adst, N);
    k_node_alpha<<<PG, tpb, 0, stream>>>(rowptr, csr_src, asrc, adst, alpha, aself, N, E);
    k_gather<<<PG, tpb, 0, stream>>>(rowptr, csr_src, alpha, aself, xp, b1, hbuf, N, E);

    // ---------------- layer 2 ----------------
    k_xp<64><<<PG, tpb, 0, stream>>>(hbuf, W2, as2, ad2, xp, asrc, adst, N);
    k_node_alpha<<<PG, tpb, 0, stream>>>(rowptr, csr_src, asrc, adst, alpha, aself, N, E);
    k_gather<<<PG, tpb, 0, stream>>>(rowptr, csr_src, alpha, aself, xp, b2, hbuf, N, E);

    // ---------------- classifier ----------------
    k_climber<<<(G * 64 + tpb - 1) / tpb, tpb, 0, stream>>>(climber, Wc, bc, cemb, G * 64);
    k_final<<<1024, tpb, 0, stream>>>(hbuf, cemb, batch, Wm1, bm1, Wm2, bm2, (float*)d_out, N);
}

// Round 5
// 840.088 us; speedup vs baseline: 1.3549x; 1.3549x over previous
//
#include <hip/hip_runtime.h>

#define SLOPE 0.2f
#define NEG_INF -3.4e38f

__device__ __forceinline__ float lrelu(float v) { return v >= 0.f ? v : SLOPE * v; }

// ============================================================================
// xp = x @ W (K -> 128 = 2 heads * 64) fused with attention dots.
// Persistent: wave-pair per node (wave h = head h); W column in registers.
// ============================================================================
template <int K>
__global__ __launch_bounds__(256, 4)
void k_xp(const float* __restrict__ x, const float* __restrict__ W,
          const float* __restrict__ as_, const float* __restrict__ ad_,
          float* __restrict__ xp, float* __restrict__ asrc,
          float* __restrict__ adst, int N) {
    int tid = blockIdx.x * blockDim.x + threadIdx.x;
    int lane = threadIdx.x & 63;
    int h = (threadIdx.x >> 6) & 1;
    int pair = tid >> 7;
    int npairs = (gridDim.x * blockDim.x) >> 7;
    int c = h * 64 + lane;

    float wreg[K];
    #pragma unroll
    for (int k = 0; k < K; ++k) wreg[k] = W[k * 128 + c];
    float asv = as_[c], adv = ad_[c];

    for (int n = pair; n < N; n += npairs) {
        float xv = (lane < K) ? x[(size_t)n * K + lane] : 0.f;
        float acc0 = 0.f, acc1 = 0.f;
        #pragma unroll
        for (int k = 0; k < K; k += 2) {
            acc0 += __shfl(xv, k, 64) * wreg[k];
            if (k + 1 < K) acc1 += __shfl(xv, k + 1, 64) * wreg[k + 1];
        }
        float acc = acc0 + acc1;
        xp[(size_t)n * 128 + c] = acc;
        float ps = acc * asv, pd = acc * adv;
        for (int off = 32; off > 0; off >>= 1) {
            ps += __shfl_xor(ps, off, 64);
            pd += __shfl_xor(pd, off, 64);
        }
        if (lane == 0) { asrc[n * 2 + h] = ps; adst[n * 2 + h] = pd; }
    }
}

// ============================================================================
// CSR build: histogram -> exclusive scan -> scatter (counting sort by dst)
// ============================================================================
__global__ void k_hist(const int* __restrict__ dst, int* __restrict__ deg, int E) {
    for (int e = blockIdx.x * blockDim.x + threadIdx.x; e < E; e += gridDim.x * blockDim.x)
        atomicAdd(&deg[dst[e]], 1);
}

__global__ void k_scan_partial(const int* __restrict__ deg, int* __restrict__ partial, int N) {
    int b = blockIdx.x, t = threadIdx.x;
    int base = b * 1024 + t * 4;
    int s = 0;
    for (int i = 0; i < 4; ++i) { int idx = base + i; if (idx < N) s += deg[idx]; }
    __shared__ int sh[256];
    sh[t] = s; __syncthreads();
    for (int off = 128; off > 0; off >>= 1) { if (t < off) sh[t] += sh[t + off]; __syncthreads(); }
    if (t == 0) partial[b] = sh[0];
}

__global__ void k_scan_partials(int* __restrict__ partial, int nb) {
    __shared__ int sh[256];
    __shared__ int carry;
    int t = threadIdx.x;
    if (t == 0) carry = 0;
    __syncthreads();
    for (int base = 0; base < nb; base += 256) {
        int idx = base + t;
        int orig = (idx < nb) ? partial[idx] : 0;
        sh[t] = orig; __syncthreads();
        for (int off = 1; off < 256; off <<= 1) {
            int v = (t >= off) ? sh[t - off] : 0;
            __syncthreads();
            sh[t] += v;
            __syncthreads();
        }
        if (idx < nb) partial[idx] = carry + sh[t] - orig;
        __syncthreads();
        if (t == 0) carry += sh[255];
        __syncthreads();
    }
}

__global__ void k_scan_final(const int* __restrict__ deg, const int* __restrict__ partial,
                             int* __restrict__ rowptr, int N, int E) {
    int b = blockIdx.x, t = threadIdx.x;
    int base = b * 1024 + t * 4;
    int local[4]; int s = 0;
    for (int i = 0; i < 4; ++i) { int idx = base + i; local[i] = (idx < N) ? deg[idx] : 0; s += local[i]; }
    __shared__ int sh[256];
    int orig = s;
    sh[t] = s; __syncthreads();
    for (int off = 1; off < 256; off <<= 1) {
        int v = (t >= off) ? sh[t - off] : 0;
        __syncthreads();
        sh[t] += v;
        __syncthreads();
    }
    int run = partial[b] + sh[t] - orig;
    for (int i = 0; i < 4; ++i) {
        int idx = base + i;
        if (idx < N) rowptr[idx] = run;
        run += local[i];
    }
    if (b == 0 && t == 0) rowptr[N] = E;
}

__global__ void k_scatter(const int* __restrict__ src, const int* __restrict__ dst,
                          const int* __restrict__ rowptr, int* __restrict__ cur,
                          int* __restrict__ csr_src, int E) {
    for (int e = blockIdx.x * blockDim.x + threadIdx.x; e < E; e += gridDim.x * blockDim.x) {
        int d = dst[e];
        int pos = atomicAdd(&cur[d], 1);
        csr_src[rowptr[d] + pos] = src[e];
    }
}

// ============================================================================
// Per-node softmax -> alpha planes. Persistent wave-pair per node (wave=head).
// ============================================================================
__global__ void k_node_alpha(const int* __restrict__ rowptr, const int* __restrict__ csr_src,
                             const float* __restrict__ asrc, const float* __restrict__ adst,
                             float* __restrict__ alpha, float* __restrict__ aself,
                             int N, int E) {
    int tid = blockIdx.x * blockDim.x + threadIdx.x;
    int lane = threadIdx.x & 63;
    int h = (threadIdx.x >> 6) & 1;
    int pair = tid >> 7;
    int npairs = (gridDim.x * blockDim.x) >> 7;

    for (int n = pair; n < N; n += npairs) {
        int rs = rowptr[n], re = rowptr[n + 1], cnt = re - rs;
        float a_dst = adst[n * 2 + h];
        float v_self = lrelu(asrc[n * 2 + h] + a_dst);

        if (cnt <= 64) {
            float v = NEG_INF;
            if (lane < cnt) {
                int s = csr_src[rs + lane];
                v = lrelu(asrc[s * 2 + h] + a_dst);
            }
            float m = fmaxf(v, v_self);
            for (int off = 32; off > 0; off >>= 1) m = fmaxf(m, __shfl_xor(m, off, 64));
            float ex = (lane < cnt) ? __expf(v - m) : 0.f;
            float exs = __expf(v_self - m);
            float den = ex + (lane == 0 ? exs : 0.f);
            for (int off = 32; off > 0; off >>= 1) den += __shfl_xor(den, off, 64);
            float inv = 1.f / (den + 1e-16f);
            if (lane < cnt) alpha[(size_t)h * E + rs + lane] = ex * inv;
            if (lane == 0) aself[(size_t)h * N + n] = exs * inv;
        } else {
            float m = v_self;
            for (int e = rs + lane; e < re; e += 64) {
                int s = csr_src[e];
                m = fmaxf(m, lrelu(asrc[s * 2 + h] + a_dst));
            }
            for (int off = 32; off > 0; off >>= 1) m = fmaxf(m, __shfl_xor(m, off, 64));
            float den = (lane == 0) ? __expf(v_self - m) : 0.f;
            for (int e = rs + lane; e < re; e += 64) {
                int s = csr_src[e];
                den += __expf(lrelu(asrc[s * 2 + h] + a_dst) - m);
            }
            for (int off = 32; off > 0; off >>= 1) den += __shfl_xor(den, off, 64);
            float inv = 1.f / (den + 1e-16f);
            for (int e = rs + lane; e < re; e += 64) {
                int s = csr_src[e];
                alpha[(size_t)h * E + e] = __expf(lrelu(asrc[s * 2 + h] + a_dst) - m) * inv;
            }
            if (lane == 0) aself[(size_t)h * N + n] = __expf(v_self - m) * inv;
        }
    }
}

// ============================================================================
// Weighted gather: ONE wave per node, both heads. 4 lane-groups of 16:
// group g -> head (g&1), edge offset (g>>1). 2x unrolled: 8 float4 gathers
// in flight per wave-iter. xor-shuffle combine; head-mean + bias + relu.
// ============================================================================
__global__ void k_gather(const int* __restrict__ rowptr, const int* __restrict__ csr_src,
                         const float* __restrict__ alpha, const float* __restrict__ aself,
                         const float* __restrict__ xp, const float* __restrict__ b,
                         float* __restrict__ hout, int N, int E) {
    int tid = blockIdx.x * blockDim.x + threadIdx.x;
    int lane = threadIdx.x & 63;
    int wid = tid >> 6;
    int nw = (gridDim.x * blockDim.x) >> 6;
    int g = lane >> 4, c4 = lane & 15;
    int h = g & 1, eo = g >> 1;
    const float4* xp4 = (const float4*)xp;
    float4 bb = ((const float4*)b)[c4];

    for (int n = wid; n < N; n += nw) {
        int rs = rowptr[n], re = rowptr[n + 1];
        float4 acc = make_float4(0.f, 0.f, 0.f, 0.f);
        if (eo == 0) {                       // self contribution on groups 0,1
            float a0 = aself[(size_t)h * N + n];
            float4 v = xp4[(size_t)n * 32 + h * 16 + c4];
            acc.x = a0 * v.x; acc.y = a0 * v.y; acc.z = a0 * v.z; acc.w = a0 * v.w;
        }
        for (int e0 = rs; e0 < re; e0 += 4) {
            int ea = e0 + eo, eb = e0 + 2 + eo;
            bool va = ea < re, vb = eb < re;
            int sa = va ? csr_src[ea] : n;
            int sb = vb ? csr_src[eb] : n;
            float aa = va ? alpha[(size_t)h * E + ea] : 0.f;
            float ab = vb ? alpha[(size_t)h * E + eb] : 0.f;
            float4 v1 = xp4[(size_t)sa * 32 + h * 16 + c4];
            float4 v2 = xp4[(size_t)sb * 32 + h * 16 + c4];
            acc.x += aa * v1.x + ab * v2.x;
            acc.y += aa * v1.y + ab * v2.y;
            acc.z += aa * v1.z + ab * v2.z;
            acc.w += aa * v1.w + ab * v2.w;
        }
        // combine even/odd edge groups (lane ^ 32), then heads (lane ^ 16)
        acc.x += __shfl_xor(acc.x, 32, 64);
        acc.y += __shfl_xor(acc.y, 32, 64);
        acc.z += __shfl_xor(acc.z, 32, 64);
        acc.w += __shfl_xor(acc.w, 32, 64);
        acc.x += __shfl_xor(acc.x, 16, 64);
        acc.y += __shfl_xor(acc.y, 16, 64);
        acc.z += __shfl_xor(acc.z, 16, 64);
        acc.w += __shfl_xor(acc.w, 16, 64);
        if (g == 0) {
            float4 r;
            r.x = fmaxf(acc.x * 0.5f + bb.x, 0.f);
            r.y = fmaxf(acc.y * 0.5f + bb.y, 0.f);
            r.z = fmaxf(acc.z * 0.5f + bb.z, 0.f);
            r.w = fmaxf(acc.w * 0.5f + bb.w, 0.f);
            ((float4*)hout)[(size_t)n * 16 + c4] = r;
        }
    }
}

// climber embed: relu(climber @ Wc + bc), [G,64]
__global__ void k_climber(const float* __restrict__ climber, const float* __restrict__ Wc,
                          const float* __restrict__ bc, float* __restrict__ cemb, int g64) {
    int i = blockIdx.x * blockDim.x + threadIdx.x;
    if (i >= g64) return;
    int g = i >> 6, c = i & 63;
    float acc = bc[c];
    for (int k = 0; k < 4; ++k) acc += climber[g * 4 + k] * Wc[k * 64 + c];
    cemb[i] = acc > 0.f ? acc : 0.f;
}

// ============================================================================
// Final MLP: persistent, one wave per node. Wm1 column (128 floats) held in
// VGPRs — __launch_bounds__(256,2) caps at 256 VGPRs so no scratch spill.
// z broadcast via shuffles; 64->4 stage via float4 butterfly reduce.
// ============================================================================
__global__ __launch_bounds__(256, 2)
void k_final(const float* __restrict__ h2, const float* __restrict__ cemb,
             const int* __restrict__ batch, const float* __restrict__ Wm1,
             const float* __restrict__ bm1, const float* __restrict__ Wm2,
             const float* __restrict__ bm2, float* __restrict__ out, int N) {
    int tid = blockIdx.x * blockDim.x + threadIdx.x;
    int lane = threadIdx.x & 63;
    int wid = tid >> 6;
    int nw = (gridDim.x * blockDim.x) >> 6;

    float w1a[64], w1b[64];
    #pragma unroll
    for (int k = 0; k < 64; ++k) w1a[k] = Wm1[k * 64 + lane];
    #pragma unroll
    for (int k = 0; k < 64; ++k) w1b[k] = Wm1[(64 + k) * 64 + lane];
    float bm1v = bm1[lane];
    float4 w2 = ((const float4*)Wm2)[lane];
    float4 bm2v = *((const float4*)bm2);

    for (int n = wid; n < N; n += nw) {
        float z0 = h2[(size_t)n * 64 + lane];
        float z1 = cemb[(size_t)batch[n] * 64 + lane];
        float acc0 = 0.f, acc1 = 0.f;
        #pragma unroll
        for (int k = 0; k < 64; k += 2) {
            acc0 += __shfl(z0, k, 64) * w1a[k];
            acc1 += __shfl(z0, k + 1, 64) * w1a[k + 1];
        }
        #pragma unroll
        for (int k = 0; k < 64; k += 2) {
            acc0 += __shfl(z1, k, 64) * w1b[k];
            acc1 += __shfl(z1, k + 1, 64) * w1b[k + 1];
        }
        float m = acc0 + acc1 + bm1v;
        m = m > 0.f ? m : 0.f;
        float4 p;
        p.x = m * w2.x; p.y = m * w2.y; p.z = m * w2.z; p.w = m * w2.w;
        for (int off = 32; off > 0; off >>= 1) {
            p.x += __shfl_xor(p.x, off, 64);
            p.y += __shfl_xor(p.y, off, 64);
            p.z += __shfl_xor(p.z, off, 64);
            p.w += __shfl_xor(p.w, off, 64);
        }
        if (lane == 0) {
            float4 o;
            o.x = p.x + bm2v.x; o.y = p.y + bm2v.y;
            o.z = p.z + bm2v.z; o.w = p.w + bm2v.w;
            ((float4*)out)[n] = o;
        }
    }
}

extern "C" void kernel_launch(void* const* d_in, const int* in_sizes, int n_in,
                              void* d_out, int out_size, void* d_ws, size_t ws_size,
                              hipStream_t stream) {
    const float* x       = (const float*)d_in[0];
    const int*   ei      = (const int*)  d_in[1];
    const int*   batch   = (const int*)  d_in[2];
    const float* climber = (const float*)d_in[3];
    const float* W1  = (const float*)d_in[4];
    const float* as1 = (const float*)d_in[5];
    const float* ad1 = (const float*)d_in[6];
    const float* b1  = (const float*)d_in[7];
    const float* W2  = (const float*)d_in[8];
    const float* as2 = (const float*)d_in[9];
    const float* ad2 = (const float*)d_in[10];
    const float* b2  = (const float*)d_in[11];
    const float* Wc  = (const float*)d_in[12];
    const float* bc  = (const float*)d_in[13];
    const float* Wm1 = (const float*)d_in[14];
    const float* bm1 = (const float*)d_in[15];
    const float* Wm2 = (const float*)d_in[16];
    const float* bm2 = (const float*)d_in[17];

    const int N  = in_sizes[0] / 6;
    const int E  = in_sizes[1] / 2;
    const int G  = in_sizes[3] / 4;

    const int* srcI = ei;
    const int* dstI = ei + E;

    // ---------------- workspace carve ----------------
    char* base = (char*)d_ws;
    size_t off = 0;
    auto carve = [&](size_t bytes) { void* p = base + off; off += (bytes + 255) & ~size_t(255); return p; };
    float* xp      = (float*)carve((size_t)N * 128 * 4);
    float* hbuf    = (float*)carve((size_t)N * 64 * 4);
    float* asrc    = (float*)carve((size_t)N * 2 * 4);
    float* adst    = (float*)carve((size_t)N * 2 * 4);
    float* cemb    = (float*)carve((size_t)G * 64 * 4);
    int*   deg     = (int*)  carve((size_t)N * 4);
    int*   rowptr  = (int*)  carve((size_t)(N + 1) * 4);
    int*   cur     = (int*)  carve((size_t)N * 4);
    int*   partial = (int*)  carve(4096 * 4);
    int*   csr_src = (int*)  carve((size_t)E * 4);
    float* alpha   = (float*)carve((size_t)E * 2 * 4);
    float* aself   = (float*)carve((size_t)N * 2 * 4);

    const int tpb = 256;
    const int nScanBlk = (N + 1023) / 1024;
    const int PG = 2048;   // persistent grid blocks

    // ---------------- CSR build (shared by both layers) ----------------
    hipMemsetAsync(deg, 0, (size_t)N * 4, stream);
    hipMemsetAsync(cur, 0, (size_t)N * 4, stream);
    k_hist<<<1024, tpb, 0, stream>>>(dstI, deg, E);
    k_scan_partial<<<nScanBlk, tpb, 0, stream>>>(deg, partial, N);
    k_scan_partials<<<1, tpb, 0, stream>>>(partial, nScanBlk);
    k_scan_final<<<nScanBlk, tpb, 0, stream>>>(deg, partial, rowptr, N, E);
    k_scatter<<<1024, tpb, 0, stream>>>(srcI, dstI, rowptr, cur, csr_src, E);

    // ---------------- layer 1 ----------------
    k_xp<6><<<PG, tpb, 0, stream>>>(x, W1, as1, ad1, xp, asrc, adst, N);
    k_node_alpha<<<PG, tpb, 0, stream>>>(rowptr, csr_src, asrc, adst, alpha, aself, N, E);
    k_gather<<<PG, tpb, 0, stream>>>(rowptr, csr_src, alpha, aself, xp, b1, hbuf, N, E);

    // ---------------- layer 2 ----------------
    k_xp<64><<<PG, tpb, 0, stream>>>(hbuf, W2, as2, ad2, xp, asrc, adst, N);
    k_node_alpha<<<PG, tpb, 0, stream>>>(rowptr, csr_src, asrc, adst, alpha, aself, N, E);
    k_gather<<<PG, tpb, 0, stream>>>(rowptr, csr_src, alpha, aself, xp, b2, hbuf, N, E);

    // ---------------- classifier ----------------
    k_climber<<<(G * 64 + tpb - 1) / tpb, tpb, 0, stream>>>(climber, Wc, bc, cemb, G * 64);
    k_final<<<1024, tpb, 0, stream>>>(hbuf, cemb, batch, Wm1, bm1, Wm2, bm2, (float*)d_out, N);
}